// Round 1
// baseline (1083.647 us; speedup 1.0000x reference)
//
#include <hip/hip_runtime.h>

// out[b,i,j,f] = x[b,i,f] * y[b,j,f]; outputs: (out, 0.75*out) concatenated.
// B=100000, 3x3 outer over i/j, F=128 features. Pure memory-bound streaming.
// float4 over f: thread t -> b = t>>5, fv = t&31 (32 float4 per 128 floats).

#define FV 32  // 128 floats / 4 per float4

__global__ __launch_bounds__(256) void tp_outer_kernel(
    const float4* __restrict__ x,
    const float4* __restrict__ y,
    float4* __restrict__ out0,
    float4* __restrict__ out1,
    int total)  // total = B * FV threads of work
{
    int tid = blockIdx.x * blockDim.x + threadIdx.x;
    if (tid >= total) return;

    int b  = tid >> 5;
    int fv = tid & 31;

    // x[b][i][*]: float4 index (b*3 + i)*FV + fv
    float4 xv0 = x[(size_t)(b * 3 + 0) * FV + fv];
    float4 xv1 = x[(size_t)(b * 3 + 1) * FV + fv];
    float4 xv2 = x[(size_t)(b * 3 + 2) * FV + fv];
    float4 yv0 = y[(size_t)(b * 3 + 0) * FV + fv];
    float4 yv1 = y[(size_t)(b * 3 + 1) * FV + fv];
    float4 yv2 = y[(size_t)(b * 3 + 2) * FV + fv];

    const float4 xs[3] = {xv0, xv1, xv2};
    const float4 ys[3] = {yv0, yv1, yv2};

    size_t obase = (size_t)b * 9 * FV + fv;

#pragma unroll
    for (int i = 0; i < 3; ++i) {
#pragma unroll
        for (int j = 0; j < 3; ++j) {
            float4 o;
            o.x = xs[i].x * ys[j].x;
            o.y = xs[i].y * ys[j].y;
            o.z = xs[i].z * ys[j].z;
            o.w = xs[i].w * ys[j].w;
            size_t oidx = obase + (size_t)(i * 3 + j) * FV;
            out0[oidx] = o;
            float4 o2;
            o2.x = 0.75f * o.x;
            o2.y = 0.75f * o.y;
            o2.z = 0.75f * o.z;
            o2.w = 0.75f * o.w;
            out1[oidx] = o2;
        }
    }
}

extern "C" void kernel_launch(void* const* d_in, const int* in_sizes, int n_in,
                              void* d_out, int out_size, void* d_ws, size_t ws_size,
                              hipStream_t stream) {
    const float4* x = (const float4*)d_in[0];
    const float4* y = (const float4*)d_in[1];

    // in_sizes[0] = B*3*128 floats
    int B = in_sizes[0] / (3 * 128);
    int total = B * FV;  // B * 32 float4-groups

    // out_size = 2 * B*9*128 floats; second output starts at half.
    float* out_f = (float*)d_out;
    float4* out0 = (float4*)out_f;
    float4* out1 = (float4*)(out_f + (size_t)out_size / 2);

    int block = 256;
    int grid = (total + block - 1) / block;
    tp_outer_kernel<<<grid, block, 0, stream>>>(x, y, out0, out1, total);
}